// Round 2
// baseline (588.234 us; speedup 1.0000x reference)
//
#include <hip/hip_runtime.h>
#include <hip/hip_cooperative_groups.h>

namespace cg = cooperative_groups;

#define XD 256
#define NI 128
#define ND 384
#define BATCH 256
#define NFUSED 6   // fused NS iterations (7 squarings total incl. analytic first)

// ---------------------------------------------------------------------------
// 32x32-tile GEMM accumulate into acc[2][2]. block = 256 threads (tx,ty in 16x16).
// AMODE: 0 = A[(m0+mm)*lda + k]     (plain)
//        1 = A[k*lda + (m0+mm)]     (A transposed)
//        2 = A[...] - A2[...]       (plain, minus second operand)
// BMODE: 0 = B[k*ldb + n]           (plain)
//        1 = B[n*ldb + k]           (B transposed)
//        2 = 2I - B (plain layout)  (Newton-Schulz operand)
// LDS layout: As[kk][mm], Bs[kk][nn], row stride 34 floats (float2-aligned).
// ---------------------------------------------------------------------------
template<int AMODE, int BMODE>
__device__ __forceinline__ void gemm32(
    const float* __restrict__ Ag, const float* __restrict__ A2, int lda,
    const float* __restrict__ Bg, int ldb,
    int m0, int n0, int Kdim,
    float* __restrict__ As, float* __restrict__ Bs,
    int tid, int tx, int ty, float acc[2][2])
{
    for (int k0 = 0; k0 < Kdim; k0 += 32) {
#pragma unroll
        for (int it = 0; it < 4; ++it) {
            int idx = tid + it * 256;
            int mm, kk;
            if (AMODE == 1) { mm = idx & 31; kk = idx >> 5; }
            else           { mm = idx >> 5; kk = idx & 31; }
            float v;
            if (AMODE == 1) v = Ag[(k0 + kk) * lda + (m0 + mm)];
            else            v = Ag[(m0 + mm) * lda + (k0 + kk)];
            if (AMODE == 2) v -= A2[(m0 + mm) * lda + (k0 + kk)];
            As[kk * 34 + mm] = v;
        }
#pragma unroll
        for (int it = 0; it < 4; ++it) {
            int idx = tid + it * 256;
            if (BMODE == 1) {
                int nn = idx >> 5, kk = idx & 31;
                Bs[kk * 34 + nn] = Bg[(n0 + nn) * ldb + (k0 + kk)];
            } else {
                int kk = idx >> 5, nn = idx & 31;
                float v = Bg[(k0 + kk) * ldb + (n0 + nn)];
                if (BMODE == 2) v = ((k0 + kk) == (n0 + nn)) ? 2.0f - v : -v;
                Bs[kk * 34 + nn] = v;
            }
        }
        __syncthreads();
#pragma unroll
        for (int kk = 0; kk < 32; ++kk) {
            float2 a = *(const float2*)(As + kk * 34 + 2 * ty);
            float2 b = *(const float2*)(Bs + kk * 34 + 2 * tx);
            acc[0][0] = fmaf(a.x, b.x, acc[0][0]);
            acc[0][1] = fmaf(a.x, b.y, acc[0][1]);
            acc[1][0] = fmaf(a.y, b.x, acc[1][0]);
            acc[1][1] = fmaf(a.y, b.y, acc[1][1]);
        }
        __syncthreads();
    }
}

// ---------------------------------------------------------------------------
// Entire solve in one cooperative kernel. Grid = 128 blocks x 256 threads.
// ---------------------------------------------------------------------------
__global__ void __launch_bounds__(256)
admm_all(const float* __restrict__ x, const float* __restrict__ parms,
         const float* __restrict__ Q, const float* __restrict__ A,
         float* __restrict__ ws, float* __restrict__ out)
{
    cg::grid_group grid = cg::this_grid();
    __shared__ float As[32 * 34];
    __shared__ float Bs[32 * 34];
    __shared__ float red[256];
    const int tid = threadIdx.x;
    const int tx = tid & 15, ty = tid >> 4;
    const int bid = blockIdx.x;

    float* Kw   = ws;                       // 256*256
    float* Yb[2] = { ws + 65536, ws + 131072 };
    float* Xb[2] = { ws + 196608, ws + 262144 };
    float* U    = ws + 327680;              // 384*384
    float* Z[2] = { ws + 475136, ws + 573440 };
    float* W    = ws + 671744;
    float* sc   = ws + 770048;

    float* xout  = out;                     // (B, XD)
    float* rgap  = out + BATCH * XD;        // (B, ND)
    float* sgap  = rgap + BATCH * ND;       // (B, ND)
    float* xhist = sgap + BATCH * ND;       // (STEPS+1, B, ND)

    // ---- phase 0: K = A^T A + Q + I  ||  state init ----
    if (bid < 64) {
        int m0 = (bid >> 3) * 32, n0 = (bid & 7) * 32;
        float acc[2][2] = {};
        gemm32<1, 0>(A, nullptr, XD, A, XD, m0, n0, NI, As, Bs, tid, tx, ty, acc);
#pragma unroll
        for (int i = 0; i < 2; ++i)
#pragma unroll
            for (int j = 0; j < 2; ++j) {
                int m = m0 + 2 * ty + i, n = n0 + 2 * tx + j;
                Kw[m * XD + n] = acc[i][j] + Q[m * XD + n] + (m == n ? 1.0f : 0.0f);
            }
    } else {
        int base = (bid - 64) * 256 + tid;
#pragma unroll
        for (int r = 0; r < 6; ++r) {
            int e = base + r * 16384;       // covers BATCH*ND = 98304
            int b = e / ND, i2 = e % ND;
            float v = (i2 < XD) ? x[b * XD + i2] : 0.0f;
            Z[0][e] = v;
            W[e] = 0.0f;
            xhist[e] = v;
        }
    }
    grid.sync();

    // ---- phase 1: Gershgorin bound -> c = 2/(2+R) ----
    if (bid == 0) {
        float s = 0.f;
        for (int j = 0; j < XD; ++j) s += fabsf(Kw[j * XD + tid]);
        red[tid] = s;
        __syncthreads();
        for (int off = 128; off; off >>= 1) {
            if (tid < off) red[tid] = fmaxf(red[tid], red[tid + off]);
            __syncthreads();
        }
        if (tid == 0) sc[0] = 2.0f / (2.0f + red[0]);
    }
    grid.sync();

    const float c = sc[0];

    // ---- phase 2: Y1 = 2cK - c^2 K^2  ||  X1 = 2cI - c^2 K ----
    if (bid < 64) {
        int m0 = (bid >> 3) * 32, n0 = (bid & 7) * 32;
        float acc[2][2] = {};
        gemm32<0, 0>(Kw, nullptr, XD, Kw, XD, m0, n0, XD, As, Bs, tid, tx, ty, acc);
#pragma unroll
        for (int i = 0; i < 2; ++i)
#pragma unroll
            for (int j = 0; j < 2; ++j) {
                int m = m0 + 2 * ty + i, n = n0 + 2 * tx + j;
                int g = m * XD + n;
                Yb[0][g] = 2.0f * c * Kw[g] - c * c * acc[i][j];
            }
    } else {
        int base = (bid - 64) * 256 + tid;
#pragma unroll
        for (int r = 0; r < 4; ++r) {
            int e = base + r * 16384;       // covers 65536
            int i2 = e >> 8, j2 = e & 255;
            float v = -c * c * Kw[e];
            if (i2 == j2) v += 2.0f * c;
            Xb[0][e] = v;
        }
    }
    grid.sync();

    // ---- phases 3..8: fused Newton-Schulz, 2 GEMMs concurrently/phase ----
    int cur = 0;
    for (int it2 = 0; it2 < NFUSED; ++it2) {
        int nxt = cur ^ 1;
        if (bid < 64) {
            int m0 = (bid >> 3) * 32, n0 = (bid & 7) * 32;
            float acc[2][2] = {};
            gemm32<0, 2>(Yb[cur], nullptr, XD, Yb[cur], XD, m0, n0, XD, As, Bs, tid, tx, ty, acc);
#pragma unroll
            for (int i = 0; i < 2; ++i)
#pragma unroll
                for (int j = 0; j < 2; ++j)
                    Yb[nxt][(m0 + 2 * ty + i) * XD + (n0 + 2 * tx + j)] = acc[i][j];
        } else {
            int t = bid - 64;
            int m0 = (t >> 3) * 32, n0 = (t & 7) * 32;
            float acc[2][2] = {};
            gemm32<0, 2>(Xb[cur], nullptr, XD, Yb[cur], XD, m0, n0, XD, As, Bs, tid, tx, ty, acc);
#pragma unroll
            for (int i = 0; i < 2; ++i)
#pragma unroll
                for (int j = 0; j < 2; ++j)
                    Xb[nxt][(m0 + 2 * ty + i) * XD + (n0 + 2 * tx + j)] = acc[i][j];
        }
        cur = nxt;
        grid.sync();
    }
    const float* Xf = Xb[cur];              // K^{-1}

    // ---- phase 9: U_TR = -X A^T || U_BL = -A X || U_TL = X ----
    if (bid < 32) {
        int m0 = (bid >> 2) * 32, n0 = (bid & 3) * 32;
        float acc[2][2] = {};
        gemm32<0, 1>(Xf, nullptr, XD, A, XD, m0, n0, XD, As, Bs, tid, tx, ty, acc);
#pragma unroll
        for (int i = 0; i < 2; ++i)
#pragma unroll
            for (int j = 0; j < 2; ++j)
                U[(m0 + 2 * ty + i) * ND + XD + (n0 + 2 * tx + j)] = -acc[i][j];
    } else if (bid < 64) {
        int t = bid - 32;
        int m0 = (t >> 3) * 32, n0 = (t & 7) * 32;
        float acc[2][2] = {};
        gemm32<0, 0>(A, nullptr, XD, Xf, XD, m0, n0, XD, As, Bs, tid, tx, ty, acc);
#pragma unroll
        for (int i = 0; i < 2; ++i)
#pragma unroll
            for (int j = 0; j < 2; ++j)
                U[(XD + m0 + 2 * ty + i) * ND + (n0 + 2 * tx + j)] = -acc[i][j];
    } else {
        int base = (bid - 64) * 256 + tid;
#pragma unroll
        for (int r = 0; r < 4; ++r) {
            int e = base + r * 16384;
            int i2 = e >> 8, j2 = e & 255;
            U[i2 * ND + j2] = Xf[e];
        }
    }
    grid.sync();

    // ---- phase 10: U_BR = -U_BL A^T ----
    if (bid < 16) {
        int m0 = (bid >> 2) * 32, n0 = (bid & 3) * 32;
        float acc[2][2] = {};
        gemm32<0, 1>(U + XD * ND, nullptr, ND, A, XD, m0, n0, XD, As, Bs, tid, tx, ty, acc);
#pragma unroll
        for (int i = 0; i < 2; ++i)
#pragma unroll
            for (int j = 0; j < 2; ++j)
                U[(XD + m0 + 2 * ty + i) * ND + XD + (n0 + 2 * tx + j)] = -acc[i][j];
    }
    grid.sync();

    // ---- phases 11..15: 5 ADMM steps ----
    for (int s = 0; s < 5; ++s) {
        const float* zin = Z[s & 1];
        float* zo = Z[(s & 1) ^ 1];
        float* xh = xhist + (size_t)(s + 1) * BATCH * ND;
        if (bid < 96) {
            int m0 = (bid / 12) * 32, n0 = (bid % 12) * 32;
            float acc[2][2] = {};
            gemm32<2, 1>(zin, parms, ND, U, ND, m0, n0, ND, As, Bs, tid, tx, ty, acc);
#pragma unroll
            for (int i = 0; i < 2; ++i)
#pragma unroll
                for (int j = 0; j < 2; ++j) {
                    int m = m0 + 2 * ty + i, n = n0 + 2 * tx + j;
                    int g = m * ND + n;
                    float xk = acc[i][j] + ((n >= XD) ? parms[g] : 0.0f);
                    float zv = zin[g];
                    float wv = W[g];
                    float v = xk + wv;
                    float lo = (n < XD) ? -1000.0f : 0.0f;
                    float ynew = fminf(fmaxf(v, lo), 1000.0f);
                    xh[g] = xk;
                    zo[g] = 2.0f * ynew - v;
                    W[g] = v - ynew;
                    if (s == 4) {
                        rgap[g] = xk - ynew;
                        sgap[g] = ynew - (zv + wv);
                        if (n < XD) xout[m * XD + n] = xk;
                    }
                }
        }
        if (s < 4) grid.sync();
    }
}

// ---------------------------------------------------------------------------
extern "C" void kernel_launch(void* const* d_in, const int* in_sizes, int n_in,
                              void* d_out, int out_size, void* d_ws, size_t ws_size,
                              hipStream_t stream)
{
    const float* x     = (const float*)d_in[0];
    const float* parms = (const float*)d_in[1];
    const float* Q     = (const float*)d_in[2];
    const float* A     = (const float*)d_in[3];
    float* ws  = (float*)d_ws;
    float* out = (float*)d_out;

    void* args[] = { (void*)&x, (void*)&parms, (void*)&Q, (void*)&A,
                     (void*)&ws, (void*)&out };
    hipLaunchCooperativeKernel((const void*)admm_all, dim3(128), dim3(256),
                               args, 0, stream);
}

// Round 4
// 516.604 us; speedup vs baseline: 1.1387x; 1.1387x over previous
//
#include <hip/hip_runtime.h>

#define XD 256
#define NI 128
#define ND 384
#define BATCH 256
#define NFUSED 6   // fused NS iterations (7 squarings total incl. analytic first)
#define NBLK 128

// ---------------------------------------------------------------------------
// Grid barrier via ONE monotonic arrival counter in a __device__ global
// (persists across graph replays; never reset — round = a / NBLK).
// Single atomic address => coherence total order => no load/RMW race.
// ---------------------------------------------------------------------------
__device__ unsigned g_arrive = 0;

__device__ __forceinline__ void gridbar()
{
    __syncthreads();
    if (threadIdx.x == 0) {
        __threadfence();   // release: make our writes visible device-wide
        unsigned a = __hip_atomic_fetch_add(&g_arrive, 1u, __ATOMIC_ACQ_REL,
                                            __HIP_MEMORY_SCOPE_AGENT);
        unsigned target = (a / NBLK + 1u) * NBLK;
        while ((int)(__hip_atomic_load(&g_arrive, __ATOMIC_RELAXED,
                                       __HIP_MEMORY_SCOPE_AGENT) - target) < 0)
            __builtin_amdgcn_s_sleep(2);
        __threadfence();   // acquire: see peers' writes
    }
    __syncthreads();
}

// ---------------------------------------------------------------------------
// 32x32-tile GEMM accumulate into acc[2][2]. block = 256 threads (tx,ty in 16x16).
// AMODE: 0 = A[m*lda+k]  1 = A[k*lda+m] (transposed)  2 = A[m*lda+k]-A2[m*lda+k]
// BMODE: 0 = B[k*ldb+n]  1 = B[n*ldb+k] (transposed)  2 = 2I - B (plain layout)
// ---------------------------------------------------------------------------
template<int AMODE, int BMODE>
__device__ __forceinline__ void gemm32(
    const float* __restrict__ Ag, const float* __restrict__ A2, int lda,
    const float* __restrict__ Bg, int ldb,
    int m0, int n0, int Kdim,
    float* __restrict__ As, float* __restrict__ Bs,
    int tid, int tx, int ty, float acc[2][2])
{
    for (int k0 = 0; k0 < Kdim; k0 += 32) {
#pragma unroll
        for (int it = 0; it < 4; ++it) {
            int idx = tid + it * 256;
            int mm, kk;
            if (AMODE == 1) { mm = idx & 31; kk = idx >> 5; }
            else           { mm = idx >> 5; kk = idx & 31; }
            float v;
            if (AMODE == 1) v = Ag[(k0 + kk) * lda + (m0 + mm)];
            else            v = Ag[(m0 + mm) * lda + (k0 + kk)];
            if (AMODE == 2) v -= A2[(m0 + mm) * lda + (k0 + kk)];
            As[kk * 34 + mm] = v;
        }
#pragma unroll
        for (int it = 0; it < 4; ++it) {
            int idx = tid + it * 256;
            if (BMODE == 1) {
                int nn = idx >> 5, kk = idx & 31;
                Bs[kk * 34 + nn] = Bg[(n0 + nn) * ldb + (k0 + kk)];
            } else {
                int kk = idx >> 5, nn = idx & 31;
                float v = Bg[(k0 + kk) * ldb + (n0 + nn)];
                if (BMODE == 2) v = ((k0 + kk) == (n0 + nn)) ? 2.0f - v : -v;
                Bs[kk * 34 + nn] = v;
            }
        }
        __syncthreads();
#pragma unroll
        for (int kk = 0; kk < 32; ++kk) {
            float2 a = *(const float2*)(As + kk * 34 + 2 * ty);
            float2 b = *(const float2*)(Bs + kk * 34 + 2 * tx);
            acc[0][0] = fmaf(a.x, b.x, acc[0][0]);
            acc[0][1] = fmaf(a.x, b.y, acc[0][1]);
            acc[1][0] = fmaf(a.y, b.x, acc[1][0]);
            acc[1][1] = fmaf(a.y, b.y, acc[1][1]);
        }
        __syncthreads();
    }
}

// ---------------------------------------------------------------------------
// Entire solve in one cooperative kernel. Grid = 128 blocks x 256 threads.
// ---------------------------------------------------------------------------
__global__ void __launch_bounds__(256)
admm_all(const float* __restrict__ x, const float* __restrict__ parms,
         const float* __restrict__ Q, const float* __restrict__ A,
         float* __restrict__ ws, float* __restrict__ out)
{
    __shared__ float As[32 * 34];
    __shared__ float Bs[32 * 34];
    __shared__ float red[256];
    const int tid = threadIdx.x;
    const int tx = tid & 15, ty = tid >> 4;
    const int bid = blockIdx.x;

    float* Kw   = ws;                       // 256*256
    float* Yb[2] = { ws + 65536, ws + 131072 };
    float* Xb[2] = { ws + 196608, ws + 262144 };
    float* U    = ws + 327680;              // 384*384
    float* Z[2] = { ws + 475136, ws + 573440 };
    float* W    = ws + 671744;

    float* xout  = out;                     // (B, XD)
    float* rgap  = out + BATCH * XD;        // (B, ND)
    float* sgap  = rgap + BATCH * ND;       // (B, ND)
    float* xhist = sgap + BATCH * ND;       // (STEPS+1, B, ND)

    // ---- phase 0: K = A^T A + Q + I  ||  state init ----
    if (bid < 64) {
        int m0 = (bid >> 3) * 32, n0 = (bid & 7) * 32;
        float acc[2][2] = {};
        gemm32<1, 0>(A, nullptr, XD, A, XD, m0, n0, NI, As, Bs, tid, tx, ty, acc);
#pragma unroll
        for (int i = 0; i < 2; ++i)
#pragma unroll
            for (int j = 0; j < 2; ++j) {
                int m = m0 + 2 * ty + i, n = n0 + 2 * tx + j;
                Kw[m * XD + n] = acc[i][j] + Q[m * XD + n] + (m == n ? 1.0f : 0.0f);
            }
    } else {
        int base = (bid - 64) * 256 + tid;
#pragma unroll
        for (int r = 0; r < 6; ++r) {
            int e = base + r * 16384;       // covers BATCH*ND = 98304
            int b = e / ND, i2 = e % ND;
            float v = (i2 < XD) ? x[b * XD + i2] : 0.0f;
            Z[0][e] = v;
            W[e] = 0.0f;
            xhist[e] = v;
        }
    }
    gridbar();

    // ---- phase 1: every block redundantly computes c = 2/(2+Gershgorin) ----
    {
        float s = 0.f;
        for (int j = 0; j < XD; ++j) s += fabsf(Kw[j * XD + tid]);
        red[tid] = s;
        __syncthreads();
        for (int off = 128; off; off >>= 1) {
            if (tid < off) red[tid] = fmaxf(red[tid], red[tid + off]);
            __syncthreads();
        }
    }
    const float c = 2.0f / (2.0f + red[0]);
    __syncthreads();

    // ---- phase 1b: Y1 = 2cK - c^2 K^2  ||  X1 = 2cI - c^2 K ----
    if (bid < 64) {
        int m0 = (bid >> 3) * 32, n0 = (bid & 7) * 32;
        float acc[2][2] = {};
        gemm32<0, 0>(Kw, nullptr, XD, Kw, XD, m0, n0, XD, As, Bs, tid, tx, ty, acc);
#pragma unroll
        for (int i = 0; i < 2; ++i)
#pragma unroll
            for (int j = 0; j < 2; ++j) {
                int m = m0 + 2 * ty + i, n = n0 + 2 * tx + j;
                int g = m * XD + n;
                Yb[0][g] = 2.0f * c * Kw[g] - c * c * acc[i][j];
            }
    } else {
        int base = (bid - 64) * 256 + tid;
#pragma unroll
        for (int r = 0; r < 4; ++r) {
            int e = base + r * 16384;       // covers 65536
            int i2 = e >> 8, j2 = e & 255;
            float v = -c * c * Kw[e];
            if (i2 == j2) v += 2.0f * c;
            Xb[0][e] = v;
        }
    }
    gridbar();

    // ---- phases 2..7: fused Newton-Schulz, 2 GEMMs concurrently/phase ----
    int cur = 0;
    for (int it2 = 0; it2 < NFUSED; ++it2) {
        int nxt = cur ^ 1;
        if (bid < 64) {
            int m0 = (bid >> 3) * 32, n0 = (bid & 7) * 32;
            float acc[2][2] = {};
            gemm32<0, 2>(Yb[cur], nullptr, XD, Yb[cur], XD, m0, n0, XD, As, Bs, tid, tx, ty, acc);
#pragma unroll
            for (int i = 0; i < 2; ++i)
#pragma unroll
                for (int j = 0; j < 2; ++j)
                    Yb[nxt][(m0 + 2 * ty + i) * XD + (n0 + 2 * tx + j)] = acc[i][j];
        } else {
            int t = bid - 64;
            int m0 = (t >> 3) * 32, n0 = (t & 7) * 32;
            float acc[2][2] = {};
            gemm32<0, 2>(Xb[cur], nullptr, XD, Yb[cur], XD, m0, n0, XD, As, Bs, tid, tx, ty, acc);
#pragma unroll
            for (int i = 0; i < 2; ++i)
#pragma unroll
                for (int j = 0; j < 2; ++j)
                    Xb[nxt][(m0 + 2 * ty + i) * XD + (n0 + 2 * tx + j)] = acc[i][j];
        }
        cur = nxt;
        gridbar();
    }
    const float* Xf = Xb[cur];              // K^{-1}

    // ---- phase 8: U_TR = -X A^T || U_BL = -A X || U_TL = X ----
    if (bid < 32) {
        int m0 = (bid >> 2) * 32, n0 = (bid & 3) * 32;
        float acc[2][2] = {};
        gemm32<0, 1>(Xf, nullptr, XD, A, XD, m0, n0, XD, As, Bs, tid, tx, ty, acc);
#pragma unroll
        for (int i = 0; i < 2; ++i)
#pragma unroll
            for (int j = 0; j < 2; ++j)
                U[(m0 + 2 * ty + i) * ND + XD + (n0 + 2 * tx + j)] = -acc[i][j];
    } else if (bid < 64) {
        int t = bid - 32;
        int m0 = (t >> 3) * 32, n0 = (t & 7) * 32;
        float acc[2][2] = {};
        gemm32<0, 0>(A, nullptr, XD, Xf, XD, m0, n0, XD, As, Bs, tid, tx, ty, acc);
#pragma unroll
        for (int i = 0; i < 2; ++i)
#pragma unroll
            for (int j = 0; j < 2; ++j)
                U[(XD + m0 + 2 * ty + i) * ND + (n0 + 2 * tx + j)] = -acc[i][j];
    } else {
        int base = (bid - 64) * 256 + tid;
#pragma unroll
        for (int r = 0; r < 4; ++r) {
            int e = base + r * 16384;
            int i2 = e >> 8, j2 = e & 255;
            U[i2 * ND + j2] = Xf[e];
        }
    }
    gridbar();

    // ---- phase 9: U_BR = -U_BL A^T ----
    if (bid < 16) {
        int m0 = (bid >> 2) * 32, n0 = (bid & 3) * 32;
        float acc[2][2] = {};
        gemm32<0, 1>(U + XD * ND, nullptr, ND, A, XD, m0, n0, XD, As, Bs, tid, tx, ty, acc);
#pragma unroll
        for (int i = 0; i < 2; ++i)
#pragma unroll
            for (int j = 0; j < 2; ++j)
                U[(XD + m0 + 2 * ty + i) * ND + XD + (n0 + 2 * tx + j)] = -acc[i][j];
    }
    gridbar();

    // ---- phases 10..14: 5 ADMM steps ----
    for (int s = 0; s < 5; ++s) {
        const float* zin = Z[s & 1];
        float* zo = Z[(s & 1) ^ 1];
        float* xh = xhist + (size_t)(s + 1) * BATCH * ND;
        if (bid < 96) {
            int m0 = (bid / 12) * 32, n0 = (bid % 12) * 32;
            float acc[2][2] = {};
            gemm32<2, 1>(zin, parms, ND, U, ND, m0, n0, ND, As, Bs, tid, tx, ty, acc);
#pragma unroll
            for (int i = 0; i < 2; ++i)
#pragma unroll
                for (int j = 0; j < 2; ++j) {
                    int m = m0 + 2 * ty + i, n = n0 + 2 * tx + j;
                    int g = m * ND + n;
                    float xk = acc[i][j] + ((n >= XD) ? parms[g] : 0.0f);
                    float zv = zin[g];
                    float wv = W[g];
                    float v = xk + wv;
                    float lo = (n < XD) ? -1000.0f : 0.0f;
                    float ynew = fminf(fmaxf(v, lo), 1000.0f);
                    xh[g] = xk;
                    zo[g] = 2.0f * ynew - v;
                    W[g] = v - ynew;
                    if (s == 4) {
                        rgap[g] = xk - ynew;
                        sgap[g] = ynew - (zv + wv);
                        if (n < XD) xout[m * XD + n] = xk;
                    }
                }
        }
        if (s < 4) gridbar();
    }
}

// ---------------------------------------------------------------------------
extern "C" void kernel_launch(void* const* d_in, const int* in_sizes, int n_in,
                              void* d_out, int out_size, void* d_ws, size_t ws_size,
                              hipStream_t stream)
{
    const float* x     = (const float*)d_in[0];
    const float* parms = (const float*)d_in[1];
    const float* Q     = (const float*)d_in[2];
    const float* A     = (const float*)d_in[3];
    float* ws  = (float*)d_ws;
    float* out = (float*)d_out;

    void* args[] = { (void*)&x, (void*)&parms, (void*)&Q, (void*)&A,
                     (void*)&ws, (void*)&out };
    hipLaunchCooperativeKernel((const void*)admm_all, dim3(NBLK), dim3(256),
                               args, 0, stream);
}